// Round 5
// baseline (18096.066 us; speedup 1.0000x reference)
//
#include <hip/hip_runtime.h>
#include <stdint.h>

#define BATCH 64
#define SEQ   2048
#define ISZ   512
#define HSZ   512
#define FH    2048   // 4*H

// workspace layout (all zeroed by the in-graph memset)
#define FLAG_OFF 0                                  // 8 chains * 32 uints = 1KB
#define HBUF_OFF 65536                              // 2 * 64*512*4 = 256KB

// ---------------------------------------------------------------------------
// Fused persistent LSTM: x-projection + recurrent scan in ONE kernel.
// 256 WGs x 512 threads (round-3 proven partition):
//   bg = bid&7  -> batch rows [bg*8, bg*8+8)
//   hg = bid>>3 -> hidden units [hg*16, hg*16+16) = 64 gate columns
// Lane layout: cg = tid&15 -> 4 gate cols; kst = tid>>4 -> k-slice [kst*16,+16).
// Each lane holds Wh block (wreg[16] float4, 64 VGPR) AND Wx block
// (wregx[16] float4, 64 VGPR), both loaded once from global.
// Per step t:
//   stage h(t) -> K-loop Wh.h -> 32-way partial reduce (+xg_c reg, computed
//   LAST step) -> gates -> cell update -> h(t+1) to L3 -> drain -> post flag
//   -> [x-proj for t+1 into xg_c, hidden in the wait] -> poll chain barrier.
// Sync skeleton is byte-for-byte round-3 (proven); the only structural change
// is compute inserted between post and poll (WG-local, barrier-safe).
// ---------------------------------------------------------------------------
__global__ __launch_bounds__(512, 1) void lstm_scan(
    const float* __restrict__ Wh0, const float* __restrict__ Wh1,
    const float* __restrict__ Wh2, const float* __restrict__ Wh3,
    const float* __restrict__ Wx0, const float* __restrict__ Wx1,
    const float* __restrict__ Wx2, const float* __restrict__ Wx3,
    const float* __restrict__ bx0, const float* __restrict__ bx1,
    const float* __restrict__ bx2, const float* __restrict__ bx3,
    const float* __restrict__ bh0, const float* __restrict__ bh1,
    const float* __restrict__ bh2, const float* __restrict__ bh3,
    const float* __restrict__ x, float* __restrict__ hbuf,
    unsigned* __restrict__ flags_base, float* __restrict__ out)
{
  extern __shared__ float hred2[];    // [32][512] = 64KB dynamic (partials)
  __shared__ float hstage[8 * 516];   // h or x rows, padded stride 516 (16.5KB)
  __shared__ float gates_s[512];      // [8 rows][64 cols]
  __shared__ float cs[128];           // [8 rows][16 units]

  const int bid = blockIdx.x;
  const int bg = bid & 7;
  const int hg = bid >> 3;
  const int b0 = bg * 8;
  const int u0 = hg * 16;
  const int tid = threadIdx.x;
  const int cg  = tid & 15;           // col quad 0..15
  const int kst = tid >> 4;           // k-slice 0..31
  const int kb  = kst * 16;           // k base for this lane

  unsigned* flags = flags_base + bg * 32;   // one 128B line per batch group

  // ---- one-time: Wh + Wx blocks into registers (128 VGPRs) -------------
  const int gate = cg >> 2;
  const float* WgH = gate == 0 ? Wh0 : gate == 1 ? Wh1 : gate == 2 ? Wh2 : Wh3;
  const float* WgX = gate == 0 ? Wx0 : gate == 1 ? Wx1 : gate == 2 ? Wx2 : Wx3;
  const int colg = u0 + (cg & 3) * 4;
  float4 wreg[16], wregx[16];
  #pragma unroll
  for (int j = 0; j < 16; ++j) {
    wreg[j]  = *(const float4*)&WgH[(size_t)(kb + j) * HSZ + colg];
    wregx[j] = *(const float4*)&WgX[(size_t)(kb + j) * HSZ + colg];
  }

  // bias for this thread's gate cell (reduce mapping: col = tid&63)
  const int bgate = (tid >> 4) & 3;
  const int bunit = u0 + (tid & 15);
  const float* bxp = bgate == 0 ? bx0 : bgate == 1 ? bx1 : bgate == 2 ? bx2 : bx3;
  const float* bhp = bgate == 0 ? bh0 : bgate == 1 ? bh1 : bgate == 2 ? bh2 : bh3;
  const float bsum = bxp[bunit] + bhp[bunit];

  // c state starts at zero
  if (tid < 128) cs[tid] = 0.f;

  // ---- x-projection for time s -> per-thread gate-cell value ----------
  auto xproj = [&](int s) -> float {
    // stage x rows [b0, b0+8) at time s: 8 x 512 floats, coalesced float4
    #pragma unroll
    for (int i = 0; i < 2; ++i) {
      int idx = tid + i * 512;                  // 0..1023 float4 units
      int r = idx >> 7, q = idx & 127;
      float4 v = *(const float4*)&x[((size_t)(b0 + r) * SEQ + s) * ISZ + q * 4];
      *(float4*)&hstage[r * 516 + q * 4] = v;
    }
    __syncthreads();
    // K-loop: 8 rows x 4 cols x 16 k per lane, Wx in regs
    float4 acc[8];
    #pragma unroll
    for (int r = 0; r < 8; ++r) acc[r] = make_float4(0.f, 0.f, 0.f, 0.f);
    #pragma unroll
    for (int jq = 0; jq < 4; ++jq) {
      float4 hv[8];
      #pragma unroll
      for (int r = 0; r < 8; ++r)
        hv[r] = *(const float4*)&hstage[r * 516 + kb + jq * 4];
      const float4 w0 = wregx[jq * 4 + 0];
      const float4 w1 = wregx[jq * 4 + 1];
      const float4 w2 = wregx[jq * 4 + 2];
      const float4 w3 = wregx[jq * 4 + 3];
      #pragma unroll
      for (int r = 0; r < 8; ++r) {
        acc[r].x += hv[r].x * w0.x; acc[r].y += hv[r].x * w0.y;
        acc[r].z += hv[r].x * w0.z; acc[r].w += hv[r].x * w0.w;
        acc[r].x += hv[r].y * w1.x; acc[r].y += hv[r].y * w1.y;
        acc[r].z += hv[r].y * w1.z; acc[r].w += hv[r].y * w1.w;
        acc[r].x += hv[r].z * w2.x; acc[r].y += hv[r].z * w2.y;
        acc[r].z += hv[r].z * w2.z; acc[r].w += hv[r].z * w2.w;
        acc[r].x += hv[r].w * w3.x; acc[r].y += hv[r].w * w3.y;
        acc[r].z += hv[r].w * w3.z; acc[r].w += hv[r].w * w3.w;
      }
    }
    #pragma unroll
    for (int r = 0; r < 8; ++r)
      *(float4*)&hred2[kst * 512 + r * 64 + cg * 4] = acc[r];
    __syncthreads();
    float s2 = 0.f;
    #pragma unroll
    for (int q = 0; q < 32; ++q) s2 += hred2[q * 512 + tid];
    return s2 + bsum;
  };

  // prologue: xg for step 0 (also covers the cs-init visibility via its syncs)
  float xg_c = xproj(0);

  for (int t = 0; t < SEQ; ++t) {
    const int par = t & 1;

    // ---- stage h rows [b0, b0+8): 16KB, agent-scope (L3) loads ----
    {
      const unsigned long long* src =
          (const unsigned long long*)(hbuf + (size_t)par * BATCH * HSZ + b0 * HSZ);
      #pragma unroll
      for (int i = 0; i < 4; ++i) {
        int idx2 = tid + i * 512;                  // 0..2047 (8B units)
        unsigned long long v =
            __hip_atomic_load(&src[idx2], __ATOMIC_RELAXED, __HIP_MEMORY_SCOPE_AGENT);
        int r = idx2 >> 8;
        int k = (idx2 & 255) * 2;
        float2 fv;
        fv.x = __uint_as_float((unsigned)(v & 0xffffffffu));
        fv.y = __uint_as_float((unsigned)(v >> 32));
        *(float2*)&hstage[r * 516 + k] = fv;
      }
    }
    __syncthreads();

    // ---- K-loop: 8 rows x 4 cols x 16 k per lane, Wh in regs ----
    {
      float4 acc[8];
      #pragma unroll
      for (int r = 0; r < 8; ++r) acc[r] = make_float4(0.f, 0.f, 0.f, 0.f);
      #pragma unroll
      for (int jq = 0; jq < 4; ++jq) {
        float4 hv[8];
        #pragma unroll
        for (int r = 0; r < 8; ++r)
          hv[r] = *(const float4*)&hstage[r * 516 + kb + jq * 4];
        const float4 w0 = wreg[jq * 4 + 0];
        const float4 w1 = wreg[jq * 4 + 1];
        const float4 w2 = wreg[jq * 4 + 2];
        const float4 w3 = wreg[jq * 4 + 3];
        #pragma unroll
        for (int r = 0; r < 8; ++r) {
          acc[r].x += hv[r].x * w0.x; acc[r].y += hv[r].x * w0.y;
          acc[r].z += hv[r].x * w0.z; acc[r].w += hv[r].x * w0.w;
          acc[r].x += hv[r].y * w1.x; acc[r].y += hv[r].y * w1.y;
          acc[r].z += hv[r].y * w1.z; acc[r].w += hv[r].y * w1.w;
          acc[r].x += hv[r].z * w2.x; acc[r].y += hv[r].z * w2.y;
          acc[r].z += hv[r].z * w2.z; acc[r].w += hv[r].z * w2.w;
          acc[r].x += hv[r].w * w3.x; acc[r].y += hv[r].w * w3.y;
          acc[r].z += hv[r].w * w3.z; acc[r].w += hv[r].w * w3.w;
        }
      }
      // write 32-way partials: hred2[kst][r][cg*4..+3]
      #pragma unroll
      for (int r = 0; r < 8; ++r)
        *(float4*)&hred2[kst * 512 + r * 64 + cg * 4] = acc[r];
    }
    __syncthreads();

    // ---- reduce 32 partials + xg (register, computed last step) ----
    {
      float s = 0.f;
      #pragma unroll
      for (int q = 0; q < 32; ++q) s += hred2[q * 512 + tid];
      gates_s[tid] = s + xg_c;
    }
    __syncthreads();

    // ---- cell update (128 cells) ----
    if (tid < 128) {
      int r = tid >> 4, uu = tid & 15;
      float gi = gates_s[r * 64 + uu];
      float gf = gates_s[r * 64 + 16 + uu];
      float gg = gates_s[r * 64 + 32 + uu];
      float go = gates_s[r * 64 + 48 + uu];
      float si = 1.f / (1.f + expf(-gi));
      float sf = 1.f / (1.f + expf(-gf));
      float tg = tanhf(gg);
      float so = 1.f / (1.f + expf(-go));
      float cn = sf * cs[tid] + si * tg;
      float hn = so * tanhf(cn);
      cs[tid] = cn;
      // h to the other parity buffer, write-through to L3 (agent scope)
      __hip_atomic_store(&hbuf[(size_t)(par ^ 1) * BATCH * HSZ + (size_t)(b0 + r) * HSZ + u0 + uu],
                         hn, __ATOMIC_RELAXED, __HIP_MEMORY_SCOPE_AGENT);
      if (t == SEQ - 1) {
        out[(b0 + r) * HSZ + u0 + uu] = hn;                     // h_t
        out[BATCH * HSZ + (b0 + r) * HSZ + u0 + uu] = cn;       // c_t
      }
    }
    // this wave's h stores must reach L3 before anyone signals
    asm volatile("s_waitcnt vmcnt(0)" ::: "memory");
    __syncthreads();

    // ---- post our flag EARLY, then hide x-proj(t+1) in the wait ----
    if (tid == 0)
      __hip_atomic_store(&flags[hg], (unsigned)(t + 1), __ATOMIC_RELAXED, __HIP_MEMORY_SCOPE_AGENT);

    xg_c = xproj(t + 1 < SEQ ? t + 1 : t);   // WG-local; barrier-safe

    // ---- leaderless barrier among the 32 WGs of this batch group ----
    if (tid < 64) {
      unsigned target = (unsigned)(t + 1);
      for (;;) {
        unsigned v = target;
        if (tid < 32)
          v = __hip_atomic_load(&flags[tid], __ATOMIC_RELAXED, __HIP_MEMORY_SCOPE_AGENT);
        if (__all((int)(v >= target))) break;
        __builtin_amdgcn_s_sleep(1);
      }
    }
    __syncthreads();
  }
}

// ---------------------------------------------------------------------------
extern "C" void kernel_launch(void* const* d_in, const int* in_sizes, int n_in,
                              void* d_out, int out_size, void* d_ws, size_t ws_size,
                              hipStream_t stream) {
  (void)in_sizes; (void)n_in; (void)out_size;
  const float* x = (const float*)d_in[0];
  const float* Wx[4] = {(const float*)d_in[1], (const float*)d_in[5],
                        (const float*)d_in[9], (const float*)d_in[13]};
  const float* Wh[4] = {(const float*)d_in[2], (const float*)d_in[6],
                        (const float*)d_in[10], (const float*)d_in[14]};
  const float* bx[4] = {(const float*)d_in[3], (const float*)d_in[7],
                        (const float*)d_in[11], (const float*)d_in[15]};
  const float* bh[4] = {(const float*)d_in[4], (const float*)d_in[8],
                        (const float*)d_in[12], (const float*)d_in[16]};
  float* out = (float*)d_out;
  char* ws = (char*)d_ws;

  if (ws_size < (1u << 20)) return;

  unsigned* flags = (unsigned*)(ws + FLAG_OFF);
  float* hbuf = (float*)(ws + HBUF_OFF);

  // allow 64KB dynamic LDS for the scan kernel (idempotent, not a stream op)
  hipFuncSetAttribute((const void*)lstm_scan,
                      hipFuncAttributeMaxDynamicSharedMemorySize, 65536);

  // zero flags + h state (ws is poisoned 0xAA before every call)
  hipMemsetAsync(d_ws, 0, (size_t)1 << 20, stream);

  const float* h0 = Wh[0]; const float* h1 = Wh[1];
  const float* h2 = Wh[2]; const float* h3 = Wh[3];
  const float* x0 = Wx[0]; const float* x1 = Wx[1];
  const float* x2 = Wx[2]; const float* x3 = Wx[3];
  const float* bx0 = bx[0]; const float* bx1 = bx[1];
  const float* bx2 = bx[2]; const float* bx3 = bx[3];
  const float* bh0 = bh[0]; const float* bh1 = bh[1];
  const float* bh2 = bh[2]; const float* bh3 = bh[3];
  const float* xp = x;
  float* hbp = hbuf; unsigned* flp = flags; float* outp = out;
  void* args[] = {&h0, &h1, &h2, &h3, &x0, &x1, &x2, &x3,
                  &bx0, &bx1, &bx2, &bx3, &bh0, &bh1, &bh2, &bh3,
                  &xp, &hbp, &flp, &outp};
  hipLaunchCooperativeKernel((const void*)lstm_scan, dim3(256), dim3(512),
                             args, 65536, stream);
}